// Round 3
// baseline (161.037 us; speedup 1.0000x reference)
//
#include <hip/hip_runtime.h>

// R13: barrier-free single-wave recurrence. B=4096, L=256, H=32, D=2.
// 256 WGs x 256 threads; each of the 4 waves owns 4 batches end-to-end and
// never syncs during the 255-step loop (barriers only around staging and
// the post-phase). R12 post-mortem: a recurrence's step wall = its own
// latency chain; the LDS+__syncthreads h-exchange (~400+ cyc with skew)
// dominated. Here h never touches LDS:
//  - each lane owns 2 cells (u1=8g+oct, u2=u1+4, batch b=m&3) and packs
//    h(u1)|h(u2) bf16 into ONE dword p.
//  - next step's B-frag (lane needs h[8*oct+j][b], j=0..7) comes from 4
//    ds_bpermute of p (owners (j<<4)|(oct<<2)|b, j=0..3; lo/hi halves) +
//    4 v_perm_b32 to assemble the bf16x8 — an in-wave crossbar, ~50 cyc.
//  - gates: 8 MFMAs, tile t rows i=(q=i&3,ur=i>>2) -> gate q of unit
//    4t+ur, cols = 4 batches x 4 dup (dup unavoidable at 4 batches/wave);
//    bias+Wi*spin pre-folded into MFMA C-in (even tiles cb0, odd cb1 —
//    correct for each lane's own extracted rows, garbage rows discarded).
//  - head logits free-ish: 9th MFMA with Wo in rows 0,1 -> acc[0],acc[1]
//    of oct==0 lanes, stored straight to Sbuf.
//  - lane extracts its 8 gate values from tiles (2g, 2g+1) via 24 cndmask.
// Cell math (combined-rcp, 7 transcendentals) and post-phase ELU/log-
// softmax carried from R12.

typedef __attribute__((ext_vector_type(8))) short bf16x8;
typedef __attribute__((ext_vector_type(4))) float f32x4;
typedef __attribute__((ext_vector_type(4))) unsigned int u32x4;

#define LOG2E 1.4426950408889634f
#define LN2   0.6931471805599453f

__device__ __forceinline__ float fexp2(float x) { return __builtin_amdgcn_exp2f(x); }
__device__ __forceinline__ float flog2(float x) { return __builtin_amdgcn_logf(x); }
__device__ __forceinline__ float frcp(float x)  { return __builtin_amdgcn_rcpf(x); }

__device__ __forceinline__ float fsig(float x)   { return frcp(1.f + fexp2(-LOG2E * x)); }
__device__ __forceinline__ float ftanh_(float x) { return 1.f - 2.f * frcp(fexp2(2.f * LOG2E * x) + 1.f); }
__device__ __forceinline__ float felu(float x)   { return x > 0.f ? x : fexp2(LOG2E * x) - 1.f; }

__device__ __forceinline__ unsigned short f2bf(float f) {   // RNE f32->bf16
    unsigned u = __builtin_bit_cast(unsigned, f);
    u = (u + 0x7FFFu + ((u >> 16) & 1u)) >> 16;
    return (unsigned short)u;
}

constexpr int Bsz = 4096;

__global__ __launch_bounds__(256, 1) void lstm_r13(
    const int*   __restrict__ x,    // [B, 256]
    const float* __restrict__ Wi,   // [2, 128]
    const float* __restrict__ Wh,   // [32, 128]
    const float* __restrict__ bh,   // [128]
    const float* __restrict__ Wo,   // [32, 2]
    const float* __restrict__ bo,   // [2]
    float*       __restrict__ out)  // [B]
{
    const int tid  = threadIdx.x;
    const int wv   = tid >> 6;      // wave 0..3
    const int lane = tid & 63;
    const int m    = lane & 15;     // MFMA column
    const int oct  = lane >> 4;
    const int g    = (m >> 2) & 3;  // column dup-group -> tile pair (2g,2g+1)
    const int b    = m & 3;         // batch within wave
    const int mb   = 4 * wv + b;    // batch within WG
    const int b0   = blockIdx.x * 16;

    __shared__ char   spinT[16][260];   // [batch][t] bytes, padded row
    __shared__ float2 Sbuf[256][16];    // raw logits (S0,S1) per (t,batch)
    __shared__ float  red[16][16];

    // ---- stage spins: 256 threads x 16 ints ----
    {
        const int bl  = tid >> 4;          // row 0..15
        const int c16 = (tid & 15) * 16;   // 16 time-cols per thread
        const int4* src = reinterpret_cast<const int4*>(x + (b0 + bl) * 256 + c16);
#pragma unroll
        for (int q = 0; q < 4; ++q) {
            const int4 v = src[q];
            const int pk = (v.x & 1) | ((v.y & 1) << 8) | ((v.z & 1) << 16) | ((v.w & 1) << 24);
            *reinterpret_cast<int*>(&spinT[bl][c16 + 4 * q]) = pk;
        }
    }

    // ---- A-frags: tile t, row i=(q=i&3, ur=i>>2) -> gs(q)*Wh[k][32q+4t+ur]
    bf16x8 wfrag[8];
    {
        const int qa = m & 3, ua = m >> 2;
        const float gsq = (qa == 2) ? 2.f * LOG2E : -LOG2E;
#pragma unroll
        for (int t8 = 0; t8 < 8; ++t8) {
            const int colg = 32 * qa + 4 * t8 + ua;
#pragma unroll
            for (int j = 0; j < 8; ++j)
                wfrag[t8][j] = (short)f2bf(gsq * Wh[(8 * oct + j) * 128 + colg]);
        }
    }
    bf16x8 wfragO;   // head: Wo cols in rows 0,1
#pragma unroll
    for (int j = 0; j < 8; ++j)
        wfragO[j] = (m < 2) ? (short)f2bf(Wo[(8 * oct + j) * 2 + m]) : (short)0;

    // ---- this lane's two cells + scaled biases ----
    const int u1 = 8 * g + oct, u2 = u1 + 4;
    float bv00[4], bvd0[4], bv01[4], bvd1[4];
#pragma unroll
    for (int r = 0; r < 4; ++r) {
        const float gsr = (r == 2) ? 2.f * LOG2E : -LOG2E;
        const int cA = 32 * r + u1, cB = 32 * r + u2;
        bv00[r] = gsr * (bh[cA] + Wi[cA]); bvd0[r] = gsr * (Wi[128 + cA] - Wi[cA]);
        bv01[r] = gsr * (bh[cB] + Wi[cB]); bvd1[r] = gsr * (Wi[128 + cB] - Wi[cB]);
    }
    const float bo0 = bo[0], bo1 = bo[1];

    // ---- bpermute owner addresses (constant per lane) ----
    const int ad0 = 4 * ((0 << 4) | (oct << 2) | b);
    const int ad1 = 4 * ((1 << 4) | (oct << 2) | b);
    const int ad2 = 4 * ((2 << 4) | (oct << 2) | b);
    const int ad3 = 4 * ((3 << 4) | (oct << 2) | b);

    __syncthreads();   // spins staged

    // ---- peel t=0: input zeros, h=c=0 -> gates = bh ----
    float c1 = fsig(bh[u1]) * ftanh_(bh[64 + u1]);
    float c2 = fsig(bh[u2]) * ftanh_(bh[64 + u2]);
    unsigned p = (unsigned)f2bf(fsig(bh[96 + u1]) * ftanh_(c1))
               | ((unsigned)f2bf(fsig(bh[96 + u2]) * ftanh_(c2)) << 16);

    const f32x4 zero4 = { 0.f, 0.f, 0.f, 0.f };

    auto cellup = [](float a0, float a1, float a2, float a3, float& cc) -> float {
        const float ei = fexp2(a0), ef = fexp2(a1);
        const float eg = fexp2(a2), eo = fexp2(a3);
        const float P = (1.f + ei) * (1.f + eg);
        const float Q = 1.f + ef;
        const float R = frcp(P * Q);
        cc = fmaf(P * R, cc, (eg - 1.f) * Q * R);   // sig(f)*c + sig(i)*tanh(g)
        const float ec = fexp2(2.f * LOG2E * cc);
        return (ec - 1.f) * frcp((1.f + eo) * (1.f + ec));   // sig(o)*tanh(c)
    };

    // one step: exchange h(t-1) in-wave, 9 MFMAs, select gates, cell update
    auto step = [&](const int t, const float spf) {
        const int P0 = __builtin_amdgcn_ds_bpermute(ad0, (int)p);
        const int P1 = __builtin_amdgcn_ds_bpermute(ad1, (int)p);
        const int P2 = __builtin_amdgcn_ds_bpermute(ad2, (int)p);
        const int P3 = __builtin_amdgcn_ds_bpermute(ad3, (int)p);

        f32x4 cb0, cb1;   // bias into MFMA C-in (off the exchange chain)
#pragma unroll
        for (int r = 0; r < 4; ++r) {
            cb0[r] = fmaf(spf, bvd0[r], bv00[r]);
            cb1[r] = fmaf(spf, bvd1[r], bv01[r]);
        }

        const unsigned d0 = __builtin_amdgcn_perm((unsigned)P1, (unsigned)P0, 0x05040100u);
        const unsigned d1 = __builtin_amdgcn_perm((unsigned)P3, (unsigned)P2, 0x05040100u);
        const unsigned d2 = __builtin_amdgcn_perm((unsigned)P1, (unsigned)P0, 0x07060302u);
        const unsigned d3 = __builtin_amdgcn_perm((unsigned)P3, (unsigned)P2, 0x07060302u);
        u32x4 hv; hv[0] = d0; hv[1] = d1; hv[2] = d2; hv[3] = d3;
        const bf16x8 hfrag = __builtin_bit_cast(bf16x8, hv);

        f32x4 aq[8];
#pragma unroll
        for (int t8 = 0; t8 < 8; ++t8)
            aq[t8] = __builtin_amdgcn_mfma_f32_16x16x32_bf16(
                wfrag[t8], hfrag, (t8 & 1) ? cb1 : cb0, 0, 0, 0);
        const f32x4 accO = __builtin_amdgcn_mfma_f32_16x16x32_bf16(
            wfragO, hfrag, zero4, 0, 0, 0);
        if (oct == 0 && m < 4)
            Sbuf[t - 1][4 * wv + m] = make_float2(accO[0], accO[1]);

        // gate select: lane's tiles are (2g, 2g+1), reg r = gate q
        const bool gb0 = (g & 1), gb1_ = (g & 2);
        float ge[4], go_[4];
#pragma unroll
        for (int r = 0; r < 4; ++r) {
            const float eA = gb1_ ? aq[4][r] : aq[0][r];
            const float eB = gb1_ ? aq[6][r] : aq[2][r];
            ge[r] = gb0 ? eB : eA;
            const float oA = gb1_ ? aq[5][r] : aq[1][r];
            const float oB = gb1_ ? aq[7][r] : aq[3][r];
            go_[r] = gb0 ? oB : oA;
        }
        const float h1 = cellup(ge[0],  ge[1],  ge[2],  ge[3],  c1);
        const float h2 = cellup(go_[0], go_[1], go_[2], go_[3], c2);
        p = (unsigned)f2bf(h1) | ((unsigned)f2bf(h2) << 16);
    };

    // spins for pair (tb, tb+1) = bytes (tb-1, tb), prefetched a pair ahead
    unsigned sp2 = *reinterpret_cast<const unsigned short*>(&spinT[mb][0]);
    for (int tb = 1; tb < 255; tb += 2) {
        const unsigned sp2n =
            *reinterpret_cast<const unsigned short*>(&spinT[mb][tb + 1]);
        step(tb,     (float)(sp2 & 0xFFu));
        step(tb + 1, (float)(sp2 >> 8));
        sp2 = sp2n;
    }
    step(255, (float)(sp2 & 0xFFu));   // uses spin 254

    // ---- tail: head logits of step 255 from h_255 ----
    {
        const int P0 = __builtin_amdgcn_ds_bpermute(ad0, (int)p);
        const int P1 = __builtin_amdgcn_ds_bpermute(ad1, (int)p);
        const int P2 = __builtin_amdgcn_ds_bpermute(ad2, (int)p);
        const int P3 = __builtin_amdgcn_ds_bpermute(ad3, (int)p);
        const unsigned d0 = __builtin_amdgcn_perm((unsigned)P1, (unsigned)P0, 0x05040100u);
        const unsigned d1 = __builtin_amdgcn_perm((unsigned)P3, (unsigned)P2, 0x05040100u);
        const unsigned d2 = __builtin_amdgcn_perm((unsigned)P1, (unsigned)P0, 0x07060302u);
        const unsigned d3 = __builtin_amdgcn_perm((unsigned)P3, (unsigned)P2, 0x07060302u);
        u32x4 hv; hv[0] = d0; hv[1] = d1; hv[2] = d2; hv[3] = d3;
        const bf16x8 hfrag = __builtin_bit_cast(bf16x8, hv);
        const f32x4 accO = __builtin_amdgcn_mfma_f32_16x16x32_bf16(
            wfragO, hfrag, zero4, 0, 0, 0);
        if (oct == 0 && m < 4)
            Sbuf[255][4 * wv + m] = make_float2(accO[0], accO[1]);
    }
    __syncthreads();

    // ---- post phase: ELU + log-softmax + sum over t ----
    float lp = 0.f;
    {
        const int bpost = tid & 15;     // batch within WG
        const int tc    = tid >> 4;     // time chunk 0..15
#pragma unroll
        for (int i = 0; i < 16; ++i) {
            const int t = tc * 16 + i;
            const float2 sv = Sbuf[t][bpost];
            const int sp = spinT[bpost][t];
            const float o0 = felu(sv.x + bo0);
            const float o1 = felu(sv.y + bo1);
            const float mx = fmaxf(o0, o1), mn = fminf(o0, o1);
            const float lse = mx + LN2 * flog2(1.f + fexp2(LOG2E * (mn - mx)));
            lp += (sp ? o1 : o0) - lse;
        }
        red[tc][bpost] = lp;
    }
    __syncthreads();
    if (tid < 16) {
        float s = 0.f;
#pragma unroll
        for (int tc2 = 0; tc2 < 16; ++tc2) s += red[tc2][tid];
        out[b0 + tid] = 0.5f * s;
    }
}

extern "C" void kernel_launch(void* const* d_in, const int* in_sizes, int n_in,
                              void* d_out, int out_size, void* d_ws, size_t ws_size,
                              hipStream_t stream) {
    const int*   x  = (const int*)d_in[0];
    const float* Wi = (const float*)d_in[1];
    const float* Wh = (const float*)d_in[2];
    const float* bh = (const float*)d_in[3];
    const float* Wo = (const float*)d_in[4];
    const float* bo = (const float*)d_in[5];
    float* out = (float*)d_out;

    // 256 WGs on 256 CUs, 4 waves/WG -> 1 wave per SIMD, no in-loop barriers.
    lstm_r13<<<dim3(Bsz / 16), dim3(256), 0, stream>>>(x, Wi, Wh, bh, Wo, bo, out);
}